// Round 5
// baseline (55.158 us; speedup 1.0000x reference)
//
#include <hip/hip_runtime.h>

#define H 1024
#define S 2048
#define B 32

// Kernel A: v[b,h] = sum_o hidden[b,o] * W[o,h], 2 b's per block.
__global__ __launch_bounds__(1024) void proj_hidden_kernel(
    const float* __restrict__ hidden, const float* __restrict__ W,
    float* __restrict__ v)
{
    const int tx = threadIdx.x & 15;       // quad within block
    const int ty = threadIdx.x >> 4;       // 0..63, o-chunk of 16
    const int q  = blockIdx.x * 16 + tx;   // global float4 column 0..255
    const int b0 = blockIdx.y * 2;
    const float4* W4 = reinterpret_cast<const float4*>(W);
    const float* h0 = hidden + b0 * H;
    const float* h1 = h0 + H;

    float4 a0 = {0.f, 0.f, 0.f, 0.f}, a1 = {0.f, 0.f, 0.f, 0.f};
#pragma unroll
    for (int i = 0; i < 16; ++i) {
        const int o = ty * 16 + i;
        const float4 w = W4[(size_t)o * (H / 4) + q];
        const float s0 = h0[o], s1 = h1[o];
        a0.x += s0 * w.x; a0.y += s0 * w.y; a0.z += s0 * w.z; a0.w += s0 * w.w;
        a1.x += s1 * w.x; a1.y += s1 * w.y; a1.z += s1 * w.z; a1.w += s1 * w.w;
    }

    __shared__ float4 red[32][16][2];      // 16 KB
#pragma unroll
    for (int step = 32; step >= 1; step >>= 1) {
        if (ty >= step && ty < 2 * step) {
            red[ty - step][tx][0] = a0;
            red[ty - step][tx][1] = a1;
        }
        __syncthreads();
        if (ty < step) {
            const float4 r0 = red[ty][tx][0], r1 = red[ty][tx][1];
            a0.x += r0.x; a0.y += r0.y; a0.z += r0.z; a0.w += r0.w;
            a1.x += r1.x; a1.y += r1.y; a1.z += r1.z; a1.w += r1.w;
        }
        __syncthreads();
    }
    if (ty == 0) {
        reinterpret_cast<float4*>(v + (size_t)b0 * H)[q] = a0;
        reinterpret_cast<float4*>(v + (size_t)(b0 + 1) * H)[q] = a1;
    }
}

// Kernel B: energies[b,s] = dot(enc[s,b,:], v[b,:])
// 8 rows per wave, explicit 2-deep pipeline (prefetch row r+1 while dotting
// row r) -> ~75 VGPR, ~24 waves/CU, steady load stream. Plain cached loads
// (nt proved neutral-to-useless; MALL not steerable). 10-shuffle merge tree;
// lanes 0..7 hold rows 0..7.
__global__ __launch_bounds__(256) void energies_kernel(
    const float* __restrict__ enc, const float* __restrict__ v,
    float* __restrict__ e)
{
    const int lane = threadIdx.x & 63;
    const int wave = threadIdx.x >> 6;
    const int b = blockIdx.y;
    const int s_base = blockIdx.x * 32 + wave * 8;

    const float4* v4 = reinterpret_cast<const float4*>(v + b * H);
    float4 vr[4];
#pragma unroll
    for (int k = 0; k < 4; ++k) vr[k] = v4[k * 64 + lane];

    const float4* row = reinterpret_cast<const float4*>(
        enc + ((size_t)s_base * B + b) * H);
    const int row_stride = B * H / 4;      // float4 stride between s rows

    float4 cur[4], nxt[4];
#pragma unroll
    for (int k = 0; k < 4; ++k) cur[k] = row[k * 64 + lane];

    float acc[8];
#pragma unroll
    for (int r = 0; r < 8; ++r) {
        if (r < 7) {
            const float4* nrow = row + (size_t)(r + 1) * row_stride;
#pragma unroll
            for (int k = 0; k < 4; ++k) nxt[k] = nrow[k * 64 + lane];
        }
        float a = 0.f;
#pragma unroll
        for (int k = 0; k < 4; ++k)
            a += cur[k].x * vr[k].x + cur[k].y * vr[k].y +
                 cur[k].z * vr[k].z + cur[k].w * vr[k].w;
        acc[r] = a;
#pragma unroll
        for (int k = 0; k < 4; ++k) cur[k] = nxt[k];
    }

    float t[4];
#pragma unroll
    for (int j = 0; j < 4; ++j) {            // xor 1: 8 -> 4
        const float a = acc[2 * j], c = acc[2 * j + 1];
        const float send = (lane & 1) ? a : c;
        const float recv = __shfl_xor(send, 1, 64);
        t[j] = ((lane & 1) ? c : a) + recv;
    }
#pragma unroll
    for (int j = 0; j < 2; ++j) {            // xor 2: 4 -> 2
        const float a = t[2 * j], c = t[2 * j + 1];
        const float send = (lane & 2) ? a : c;
        const float recv = __shfl_xor(send, 2, 64);
        t[j] = ((lane & 2) ? c : a) + recv;
    }
    {                                        // xor 4: 2 -> 1
        const float a = t[0], c = t[1];
        const float send = (lane & 4) ? a : c;
        const float recv = __shfl_xor(send, 4, 64);
        t[0] = ((lane & 4) ? c : a) + recv;
    }
    t[0] += __shfl_xor(t[0], 8, 64);
    t[0] += __shfl_xor(t[0], 16, 64);
    t[0] += __shfl_xor(t[0], 32, 64);

    if (lane < 8)
        e[b * S + s_base + lane] = t[0];
}

// Kernel C: softmax over s per b. One block per b, 256 threads x 8 vals.
__global__ __launch_bounds__(256) void softmax_kernel(
    const float* __restrict__ e, float* __restrict__ out)
{
    const int b = blockIdx.x;
    const int tid = threadIdx.x;
    const int lane = tid & 63, wv = tid >> 6;

    float vals[8];
#pragma unroll
    for (int i = 0; i < 8; ++i) vals[i] = e[b * S + tid + i * 256];

    float m = vals[0];
#pragma unroll
    for (int i = 1; i < 8; ++i) m = fmaxf(m, vals[i]);
#pragma unroll
    for (int off = 32; off > 0; off >>= 1)
        m = fmaxf(m, __shfl_xor(m, off, 64));

    __shared__ float redm[4];
    __shared__ float reds[4];
    if (lane == 0) redm[wv] = m;
    __syncthreads();
    m = fmaxf(fmaxf(redm[0], redm[1]), fmaxf(redm[2], redm[3]));

    float sum = 0.f;
#pragma unroll
    for (int i = 0; i < 8; ++i) { vals[i] = __expf(vals[i] - m); sum += vals[i]; }
#pragma unroll
    for (int off = 32; off > 0; off >>= 1)
        sum += __shfl_xor(sum, off, 64);
    if (lane == 0) reds[wv] = sum;
    __syncthreads();
    sum = reds[0] + reds[1] + reds[2] + reds[3];

    const float inv = 1.f / sum;
#pragma unroll
    for (int i = 0; i < 8; ++i) out[b * S + tid + i * 256] = vals[i] * inv;
}

extern "C" void kernel_launch(void* const* d_in, const int* in_sizes, int n_in,
                              void* d_out, int out_size, void* d_ws, size_t ws_size,
                              hipStream_t stream) {
    const float* hidden = (const float*)d_in[0];   // [1,B,H]
    const float* enc    = (const float*)d_in[1];   // [S,B,H]
    const float* W      = (const float*)d_in[2];   // [H,H] (o,h)
    // d_in[3] bias: identically zero AND softmax-shift-invariant -> skipped.
    float* out = (float*)d_out;                    // [B,1,S]

    float* v = (float*)d_ws;                       // B*H floats = 128 KB
    float* e = v + B * H;                          // B*S floats = 256 KB

    proj_hidden_kernel<<<dim3(H / 64, B / 2), 1024, 0, stream>>>(hidden, W, v);
    energies_kernel<<<dim3(S / 32, B), 256, 0, stream>>>(enc, v, e);
    softmax_kernel<<<B, 256, 0, stream>>>(e, out);
}

// Round 6
// 53.646 us; speedup vs baseline: 1.0282x; 1.0282x over previous
//
#include <hip/hip_runtime.h>

#define H 1024
#define S 2048
#define B 32

// Kernel A: v[b,h] = sum_o hidden[b,o] * W[o,h], 2 b's per block.
__global__ __launch_bounds__(1024) void proj_hidden_kernel(
    const float* __restrict__ hidden, const float* __restrict__ W,
    float* __restrict__ v)
{
    const int tx = threadIdx.x & 15;       // quad within block
    const int ty = threadIdx.x >> 4;       // 0..63, o-chunk of 16
    const int q  = blockIdx.x * 16 + tx;   // global float4 column 0..255
    const int b0 = blockIdx.y * 2;
    const float4* W4 = reinterpret_cast<const float4*>(W);
    const float* h0 = hidden + b0 * H;
    const float* h1 = h0 + H;

    float4 a0 = {0.f, 0.f, 0.f, 0.f}, a1 = {0.f, 0.f, 0.f, 0.f};
#pragma unroll
    for (int i = 0; i < 16; ++i) {
        const int o = ty * 16 + i;
        const float4 w = W4[(size_t)o * (H / 4) + q];
        const float s0 = h0[o], s1 = h1[o];
        a0.x += s0 * w.x; a0.y += s0 * w.y; a0.z += s0 * w.z; a0.w += s0 * w.w;
        a1.x += s1 * w.x; a1.y += s1 * w.y; a1.z += s1 * w.z; a1.w += s1 * w.w;
    }

    __shared__ float4 red[32][16][2];      // 16 KB
#pragma unroll
    for (int step = 32; step >= 1; step >>= 1) {
        if (ty >= step && ty < 2 * step) {
            red[ty - step][tx][0] = a0;
            red[ty - step][tx][1] = a1;
        }
        __syncthreads();
        if (ty < step) {
            const float4 r0 = red[ty][tx][0], r1 = red[ty][tx][1];
            a0.x += r0.x; a0.y += r0.y; a0.z += r0.z; a0.w += r0.w;
            a1.x += r1.x; a1.y += r1.y; a1.z += r1.z; a1.w += r1.w;
        }
        __syncthreads();
    }
    if (ty == 0) {
        reinterpret_cast<float4*>(v + (size_t)b0 * H)[q] = a0;
        reinterpret_cast<float4*>(v + (size_t)(b0 + 1) * H)[q] = a1;
    }
}

// Kernel B: energies[b,s] = dot(enc[s,b,:], v[b,:])
// One block per s. enc[s][0..31][:] is a single CONTIGUOUS 128 KB span;
// the 256 threads sweep it linearly (thread tid gets float4 slot tid of
// every b-row), so consecutive blocks read consecutive 128 KB -> DRAM sees
// sequential streams (the fill-kernel pattern that hits ~6.9 TB/s).
// v[b][tid] comes from L2 (128 KB, hot). Per-b cross-thread reduce: 6-level
// in-wave merge tree (31+1 shuffles for 32 rows) + LDS cross-wave combine.
__global__ __launch_bounds__(256) void energies_kernel(
    const float* __restrict__ enc, const float* __restrict__ v,
    float* __restrict__ e)
{
    const int tid  = threadIdx.x;
    const int lane = tid & 63;
    const int wv   = tid >> 6;
    const int s    = blockIdx.x;

    const float4* row4 = reinterpret_cast<const float4*>(enc) +
                         (size_t)s * (B * H / 4);
    const float4* v4 = reinterpret_cast<const float4*>(v);

    float acc[B];
#pragma unroll
    for (int b = 0; b < B; ++b) {
        const float4 x = row4[b * 256 + tid];
        const float4 w = v4[b * 256 + tid];
        acc[b] = x.x * w.x + x.y * w.y + x.z * w.z + x.w * w.w;
    }

    // merge tree: after xor 1,2,4,8,16 each lane holds the 32-lane-group sum
    // of row (lane&31); xor 32 completes the wave. Lanes 0..31 = b 0..31.
    float t[16];
#pragma unroll
    for (int j = 0; j < 16; ++j) {
        const float a = acc[2 * j], c = acc[2 * j + 1];
        const float send = (lane & 1) ? a : c;
        const float recv = __shfl_xor(send, 1, 64);
        t[j] = ((lane & 1) ? c : a) + recv;
    }
#pragma unroll
    for (int j = 0; j < 8; ++j) {
        const float a = t[2 * j], c = t[2 * j + 1];
        const float send = (lane & 2) ? a : c;
        const float recv = __shfl_xor(send, 2, 64);
        t[j] = ((lane & 2) ? c : a) + recv;
    }
#pragma unroll
    for (int j = 0; j < 4; ++j) {
        const float a = t[2 * j], c = t[2 * j + 1];
        const float send = (lane & 4) ? a : c;
        const float recv = __shfl_xor(send, 4, 64);
        t[j] = ((lane & 4) ? c : a) + recv;
    }
#pragma unroll
    for (int j = 0; j < 2; ++j) {
        const float a = t[2 * j], c = t[2 * j + 1];
        const float send = (lane & 8) ? a : c;
        const float recv = __shfl_xor(send, 8, 64);
        t[j] = ((lane & 8) ? c : a) + recv;
    }
    {
        const float a = t[0], c = t[1];
        const float send = (lane & 16) ? a : c;
        const float recv = __shfl_xor(send, 16, 64);
        t[0] = ((lane & 16) ? c : a) + recv;
    }
    t[0] += __shfl_xor(t[0], 32, 64);

    __shared__ float red[4][B];
    if (lane < B) red[wv][lane] = t[0];
    __syncthreads();
    if (tid < B)
        e[(size_t)tid * S + s] = red[0][tid] + red[1][tid] +
                                 red[2][tid] + red[3][tid];
}

// Kernel C: softmax over s per b. One block per b, 256 threads x 8 vals.
__global__ __launch_bounds__(256) void softmax_kernel(
    const float* __restrict__ e, float* __restrict__ out)
{
    const int b = blockIdx.x;
    const int tid = threadIdx.x;
    const int lane = tid & 63, wv = tid >> 6;

    float vals[8];
#pragma unroll
    for (int i = 0; i < 8; ++i) vals[i] = e[b * S + tid + i * 256];

    float m = vals[0];
#pragma unroll
    for (int i = 1; i < 8; ++i) m = fmaxf(m, vals[i]);
#pragma unroll
    for (int off = 32; off > 0; off >>= 1)
        m = fmaxf(m, __shfl_xor(m, off, 64));

    __shared__ float redm[4];
    __shared__ float reds[4];
    if (lane == 0) redm[wv] = m;
    __syncthreads();
    m = fmaxf(fmaxf(redm[0], redm[1]), fmaxf(redm[2], redm[3]));

    float sum = 0.f;
#pragma unroll
    for (int i = 0; i < 8; ++i) { vals[i] = __expf(vals[i] - m); sum += vals[i]; }
#pragma unroll
    for (int off = 32; off > 0; off >>= 1)
        sum += __shfl_xor(sum, off, 64);
    if (lane == 0) reds[wv] = sum;
    __syncthreads();
    sum = reds[0] + reds[1] + reds[2] + reds[3];

    const float inv = 1.f / sum;
#pragma unroll
    for (int i = 0; i < 8; ++i) out[b * S + tid + i * 256] = vals[i] * inv;
}

extern "C" void kernel_launch(void* const* d_in, const int* in_sizes, int n_in,
                              void* d_out, int out_size, void* d_ws, size_t ws_size,
                              hipStream_t stream) {
    const float* hidden = (const float*)d_in[0];   // [1,B,H]
    const float* enc    = (const float*)d_in[1];   // [S,B,H]
    const float* W      = (const float*)d_in[2];   // [H,H] (o,h)
    // d_in[3] bias: identically zero AND softmax-shift-invariant -> skipped.
    float* out = (float*)d_out;                    // [B,1,S]

    float* v = (float*)d_ws;                       // B*H floats = 128 KB
    float* e = v + B * H;                          // B*S floats = 256 KB

    proj_hidden_kernel<<<dim3(H / 64, B / 2), 1024, 0, stream>>>(hidden, W, v);
    energies_kernel<<<S, 256, 0, stream>>>(enc, v, e);
    softmax_kernel<<<B, 256, 0, stream>>>(e, out);
}